// Round 4
// baseline (521.314 us; speedup 1.0000x reference)
//
#include <hip/hip_runtime.h>
#include <hip/hip_fp16.h>
#include <stdint.h>
#include <math.h>

typedef _Float16 f16;
typedef _Float16 f16x8 __attribute__((ext_vector_type(8)));
typedef float f32x4 __attribute__((ext_vector_type(4)));

#define DIM_   1024
#define STATE_ 16
#define INNER_ 2048
#define BATCH_ 4
#define LSEQ_  2048
#define NROWS_ 8192
#define SEG_   16
#define SEGLEN_ 128

// ---------------------------------------------------------------- utilities
__device__ __forceinline__ void gl_lds16(const void* g, void* l) {
  __builtin_amdgcn_global_load_lds(
      (const __attribute__((address_space(1))) uint32_t*)g,
      (__attribute__((address_space(3))) uint32_t*)l,
      16, 0, 0);
}

__global__ void cvt16(const float* __restrict__ in, f16* __restrict__ out, int n) {
  int i = blockIdx.x * 256 + threadIdx.x;
  int stride = gridDim.x * 256;
  for (; i < n; i += stride) out[i] = (f16)in[i];
}

// ---------------------------------------------------------------- GEMM (8-phase, m201-style)
// C[M,N] = A[M,K] @ B[N,K]^T, f16 in, f32 acc, MFMA 16x16x32.
// Tile BM x 256, BK=64, 8 waves (2M x 4N), per-wave (BM/2) x 64.
// 8 phases per 2 K-tiles; each phase: {ds_read subtile | stage <=1 half-tile ->
// barrier -> lgkm(0) -> setprio(1) -> 16(or 8) MFMA -> setprio(0) -> barrier}.
// Counted vmcnt gates ONLY at ph4/ph8; loads span ~6 phases. XOR chunk swizzle
// (pre-swizzled global source), XCD block swizzle.
template<int MODE, int BM>
__global__ __launch_bounds__(512, 1)
void gemm8(const f16* __restrict__ A, const f16* __restrict__ B,
           int M, int N, int K,
           float* __restrict__ out0, f16* __restrict__ out1,
           f16* __restrict__ out1b, const float* __restrict__ bias)
{
  constexpr int MF = BM / 32;     // m-frags per wave
  constexpr int MH = MF / 2;
  constexpr int AL = BM / 64;     // A stage issues per K-tile per wave (4 or 2)

  __shared__ __align__(16) f16 Ab[2][BM * 64];
  __shared__ __align__(16) f16 Bb[2][256 * 64];

  const int tid = threadIdx.x;
  const int l   = tid & 63;
  const int w   = tid >> 6;          // 0..7
  const int wr  = w >> 2;            // 0..1
  const int wc  = w & 3;             // 0..3
  const int lr  = l & 15;
  const int lk  = l >> 4;
  const int e7  = lr & 7;

  // XCD-aware swizzle (grids are multiples of 8)
  const int nbx = gridDim.x;
  int id = blockIdx.y * nbx + blockIdx.x;
  const int nwg = nbx * (int)gridDim.y;
  id = (id & 7) * (nwg >> 3) + (id >> 3);
  const int bn = (id % nbx) * 256;
  const int bm = (id / nbx) * BM;

  const int nt = K >> 6;             // K-tiles of 64 (even for all our shapes)

  // staging: one gl_lds16 per wave covers 8 rows x 128B. lane -> local row l>>3,
  // phys chunk l&7; source pre-swizzled: logical chunk = (l&7)^(l>>3).
  const int srow = w*8 + (l >> 3);
  const int scl  = (l & 7) ^ (l >> 3);
  const f16* Ag = A + (size_t)(bm + srow) * K + scl*8;
  const f16* Bg = B + (size_t)(bn + srow) * K + scl*8;

  // stage one half-tile (HALF = BM/2 rows for A, 128 rows for B)
#define SGB(DST, KT, H) { \
    gl_lds16(Bg + (size_t)((H)*128     )*K + (size_t)(KT)*64, (void*)&(DST)[((H)*128      + w*8)*64]); \
    gl_lds16(Bg + (size_t)((H)*128 + 64)*K + (size_t)(KT)*64, (void*)&(DST)[((H)*128 + 64 + w*8)*64]); }
#define SGA(DST, KT, H) _Pragma("unroll") for (int j = 0; j < AL/2; ++j) \
    gl_lds16(Ag + (size_t)((H)*(BM/2) + j*64)*K + (size_t)(KT)*64, \
             (void*)&(DST)[((H)*(BM/2) + j*64 + w*8)*64]);

  // read-side: logical (row r, chunk c) at phys chunk c^(r&7); r&7 == lr&7
  const int arb = (wr*(BM/2) + lr)*64;
  const int brb = (wc*64 + lr)*64;
  const int cx0 = ((lk    ) ^ e7) << 3;
  const int cx1 = ((lk + 4) ^ e7) << 3;

  f32x4 acc[MF][4];
#pragma unroll
  for (int m = 0; m < MF; ++m)
#pragma unroll
    for (int n = 0; n < 4; ++n) acc[m][n] = (f32x4){0.f,0.f,0.f,0.f};

  f16x8 a0[MH][2], a1[MH][2], b0[2][2], b1[2][2];

#define LDA0(BUF) _Pragma("unroll") for (int m = 0; m < MH; ++m) { \
    a0[m][0] = *(const f16x8*)&(BUF)[arb + m*1024 + cx0]; \
    a0[m][1] = *(const f16x8*)&(BUF)[arb + m*1024 + cx1]; }
#define LDA1(BUF) _Pragma("unroll") for (int m = 0; m < MH; ++m) { \
    a1[m][0] = *(const f16x8*)&(BUF)[arb + (m+MH)*1024 + cx0]; \
    a1[m][1] = *(const f16x8*)&(BUF)[arb + (m+MH)*1024 + cx1]; }
#define LDB0(BUF) _Pragma("unroll") for (int n = 0; n < 2; ++n) { \
    b0[n][0] = *(const f16x8*)&(BUF)[brb + n*1024 + cx0]; \
    b0[n][1] = *(const f16x8*)&(BUF)[brb + n*1024 + cx1]; }
#define LDB1(BUF) _Pragma("unroll") for (int n = 0; n < 2; ++n) { \
    b1[n][0] = *(const f16x8*)&(BUF)[brb + (n+2)*1024 + cx0]; \
    b1[n][1] = *(const f16x8*)&(BUF)[brb + (n+2)*1024 + cx1]; }

#define MM(AC, AV, BV) AC = __builtin_amdgcn_mfma_f32_16x16x32_f16(AV, BV, AC, 0, 0, 0)
  // kk-outer: 8 independent MFMAs between the two writes to each acc
#define Q0_ _Pragma("unroll") for (int kk = 0; kk < 2; ++kk) _Pragma("unroll") for (int m = 0; m < MH; ++m) \
    _Pragma("unroll") for (int n = 0; n < 2; ++n) MM(acc[m][n], a0[m][kk], b0[n][kk]);
#define Q1_ _Pragma("unroll") for (int kk = 0; kk < 2; ++kk) _Pragma("unroll") for (int m = 0; m < MH; ++m) \
    _Pragma("unroll") for (int n = 0; n < 2; ++n) MM(acc[m][n+2], a0[m][kk], b1[n][kk]);
#define Q2_ _Pragma("unroll") for (int kk = 0; kk < 2; ++kk) _Pragma("unroll") for (int m = 0; m < MH; ++m) \
    _Pragma("unroll") for (int n = 0; n < 2; ++n) MM(acc[m+MH][n], a1[m][kk], b0[n][kk]);
#define Q3_ _Pragma("unroll") for (int kk = 0; kk < 2; ++kk) _Pragma("unroll") for (int m = 0; m < MH; ++m) \
    _Pragma("unroll") for (int n = 0; n < 2; ++n) MM(acc[m+MH][n+2], a1[m][kk], b1[n][kk]);

#define GATE4 asm volatile("s_waitcnt vmcnt(4)" ::: "memory");
#define GATE8 { if constexpr (AL == 4) asm volatile("s_waitcnt vmcnt(8)" ::: "memory"); \
                else                   asm volatile("s_waitcnt vmcnt(6)" ::: "memory"); }

#define PHASE(RD, ST, GT, MQ) \
    RD ST GT \
    __builtin_amdgcn_s_barrier(); \
    asm volatile("s_waitcnt lgkmcnt(0)" ::: "memory"); \
    __builtin_amdgcn_sched_barrier(0); \
    __builtin_amdgcn_s_setprio(1); \
    MQ \
    __builtin_amdgcn_s_setprio(0); \
    __builtin_amdgcn_s_barrier();

  // prologue: tile0 -> buf0, tile1 -> buf1; gate tile0 resident
  SGB(Bb[0], 0, 0) SGB(Bb[0], 0, 1) SGA(Ab[0], 0, 0) SGA(Ab[0], 0, 1)
  SGB(Bb[1], 1, 0) SGB(Bb[1], 1, 1) SGA(Ab[1], 1, 0) SGA(Ab[1], 1, 1)
  GATE8;
  __builtin_amdgcn_s_barrier();

  for (int T = 0; T < nt; T += 2) {
    const int t2 = (T+2 < nt) ? T+2 : nt-2;   // clamped: identical restage on tail
    const int t3 = (T+3 < nt) ? T+3 : nt-1;
    // K-tile T (buf0)
    PHASE(LDA0(Ab[0]) LDB0(Bb[0]), ,                                    , Q0_)
    PHASE(LDB1(Bb[0])            , ,                                    , Q1_)
    PHASE(LDA1(Ab[0])            , SGB(Bb[0], t2, 0),                   , Q2_)
    PHASE(                       , SGB(Bb[0], t2, 1), GATE4             , Q3_)
    // K-tile T+1 (buf1)
    PHASE(LDA0(Ab[1]) LDB0(Bb[1]), SGA(Ab[0], t2, 0),                   , Q0_)
    PHASE(LDB1(Bb[1])            , SGA(Ab[0], t2, 1),                   , Q1_)
    PHASE(LDA1(Ab[1])            , SGB(Bb[1], t3, 0),                   , Q2_)
    PHASE(                       , SGB(Bb[1], t3, 1) SGA(Ab[1], t3, 0) SGA(Ab[1], t3, 1), GATE8, Q3_)
  }

  asm volatile("s_waitcnt vmcnt(0)" ::: "memory");

  // epilogue: C/D frag layout col = lane&15, row = (lane>>4)*4 + i
  const int row0 = bm + wr*(BM/2) + lk*4;
  const int col0 = bn + wc*64 + lr;
#pragma unroll
  for (int m = 0; m < MF; ++m) {
#pragma unroll
    for (int n = 0; n < 4; ++n) {
      const int c = col0 + n*16;
#pragma unroll
      for (int i = 0; i < 4; ++i) {
        const int r = row0 + m*16 + i;
        const float v = acc[m][n][i];
        if (MODE == 0) {                      // in_proj: x_in f16 | silu(res) f16
          if (c < 2048) {
            out1[(size_t)r*2048 + c] = (f16)v;
          } else {
            float sg = 1.f / (1.f + __expf(-v));
            out1b[(size_t)r*2048 + (c - 2048)] = (f16)(v * sg);
          }
        } else if (MODE == 1) {               // dt: softplus(v + bias)
          float tt = v + bias[c];
          out0[(size_t)r*2048 + c] = (tt > 15.f) ? tt : log1pf(__expf(tt));
        } else {
          out0[(size_t)r*N + c] = v;
        }
      }
    }
  }
#undef SGA
#undef SGB
#undef LDA0
#undef LDA1
#undef LDB0
#undef LDB1
#undef MM
#undef Q0_
#undef Q1_
#undef Q2_
#undef Q3_
#undef GATE4
#undef GATE8
#undef PHASE
}

// ---------------------------------------------------------------- Bm/Cm skinny GEMM
__global__ __launch_bounds__(256)
void gemm_bc(const f16* __restrict__ A, const f16* __restrict__ W,
             float* __restrict__ outBC)
{
  __shared__ __align__(16) f16 Xs[128*72];
  __shared__ __align__(16) f16 Ws[32*72];
  const int tid = threadIdx.x;
  const int l = tid & 63, w = tid >> 6;
  const int lr = l & 15, lk = l >> 4;
  const int bm = blockIdx.x * 128;

  f32x4 acc[2][2];
#pragma unroll
  for (int m = 0; m < 2; ++m)
#pragma unroll
    for (int n = 0; n < 2; ++n) acc[m][n] = (f32x4){0.f,0.f,0.f,0.f};

  for (int k0 = 0; k0 < 2048; k0 += 64) {
#pragma unroll
    for (int c = 0; c < 4; ++c) {
      int u = tid + c*256;
      int row = u >> 3, k8 = u & 7;
      *(f16x8*)&Xs[row*72 + k8*8] =
          *(const f16x8*)&A[(size_t)(bm + row)*2048 + k0 + k8*8];
    }
    { int row = tid >> 3, k8 = tid & 7;
      *(f16x8*)&Ws[row*72 + k8*8] =
          *(const f16x8*)&W[(size_t)row*2048 + k0 + k8*8]; }
    __syncthreads();
#pragma unroll
    for (int kk = 0; kk < 2; ++kk) {
      f16x8 x0 = *(const f16x8*)&Xs[(w*32      + lr)*72 + kk*32 + lk*8];
      f16x8 x1 = *(const f16x8*)&Xs[(w*32 + 16 + lr)*72 + kk*32 + lk*8];
      f16x8 w0 = *(const f16x8*)&Ws[(lr     )*72 + kk*32 + lk*8];
      f16x8 w1 = *(const f16x8*)&Ws[(16 + lr)*72 + kk*32 + lk*8];
      acc[0][0] = __builtin_amdgcn_mfma_f32_16x16x32_f16(x0, w0, acc[0][0], 0,0,0);
      acc[0][1] = __builtin_amdgcn_mfma_f32_16x16x32_f16(x0, w1, acc[0][1], 0,0,0);
      acc[1][0] = __builtin_amdgcn_mfma_f32_16x16x32_f16(x1, w0, acc[1][0], 0,0,0);
      acc[1][1] = __builtin_amdgcn_mfma_f32_16x16x32_f16(x1, w1, acc[1][1], 0,0,0);
    }
    __syncthreads();
  }
#pragma unroll
  for (int m = 0; m < 2; ++m)
#pragma unroll
    for (int n = 0; n < 2; ++n)
#pragma unroll
      for (int i = 0; i < 4; ++i) {
        int row = bm + w*32 + m*16 + lk*4 + i;
        int col = n*16 + lr;
        outBC[(size_t)row*32 + col] = acc[m][n][i];
      }
}

// ---------------------------------------------------------------- conv+silu
__global__ __launch_bounds__(256)
void conv_silu4(const f16* __restrict__ xin, const float* __restrict__ cw,
                const float* __restrict__ cb, f16* __restrict__ xc)
{
  const int idx = blockIdx.x * 256 + threadIdx.x;
  const int d  = idx & (INNER_ - 1);
  const int g  = idx >> 11;
  const int t0 = (g & 511) << 2;
  const int b  = g >> 9;
  const size_t rbase = ((size_t)b*LSEQ_ + t0)*INNER_ + d;

  const float w0 = cw[d*4], w1 = cw[d*4+1], w2 = cw[d*4+2], w3 = cw[d*4+3];
  const float bs = cb[d];
  float xm3 = 0.f, xm2 = 0.f, xm1 = 0.f;
  if (t0) {
    xm3 = (float)xin[rbase - 3*INNER_];
    xm2 = (float)xin[rbase - 2*INNER_];
    xm1 = (float)xin[rbase - 1*INNER_];
  }
  const float x0 = (float)xin[rbase];
  const float x1 = (float)xin[rbase + INNER_];
  const float x2 = (float)xin[rbase + 2*INNER_];
  const float x3 = (float)xin[rbase + 3*INNER_];

  float c0 = bs + w0*xm3 + w1*xm2 + w2*xm1 + w3*x0;
  float c1 = bs + w0*xm2 + w1*xm1 + w2*x0  + w3*x1;
  float c2 = bs + w0*xm1 + w1*x0  + w2*x1  + w3*x2;
  float c3 = bs + w0*x0  + w1*x1  + w2*x2  + w3*x3;

  xc[rbase            ] = (f16)(c0 / (1.f + __expf(-c0)));
  xc[rbase +   INNER_ ] = (f16)(c1 / (1.f + __expf(-c1)));
  xc[rbase + 2*INNER_ ] = (f16)(c2 / (1.f + __expf(-c2)));
  xc[rbase + 3*INNER_ ] = (f16)(c3 / (1.f + __expf(-c3)));
}

// ---------------------------------------------------------------- scan
__global__ __launch_bounds__(256)
void scan_local(const float* __restrict__ dt, const f16* __restrict__ xc,
                const float* __restrict__ bc32, const float* __restrict__ alog,
                float* __restrict__ Q, float* __restrict__ DTS)
{
  const int tid = threadIdx.x;
  const int b = blockIdx.z, seg = blockIdx.y, dc = blockIdx.x;
  const int d = dc*256 + tid;
  const int r0 = b*LSEQ_ + seg*SEGLEN_;

  __shared__ float bs[SEGLEN_][16];
  for (int i = tid; i < SEGLEN_*16; i += 256)
    bs[i >> 4][i & 15] = bc32[(size_t)(r0 + (i >> 4))*32 + (i & 15)];

  float Ac[16];
#pragma unroll
  for (int s = 0; s < 16; ++s) Ac[s] = -__expf(alog[d*16 + s]);
  __syncthreads();

  float st[16];
#pragma unroll
  for (int s = 0; s < 16; ++s) st[s] = 0.f;
  float dtsum = 0.f;

  for (int tt = 0; tt < SEGLEN_; ++tt) {
    const size_t idx = (size_t)(r0 + tt)*INNER_ + d;
    const float dtv = dt[idx];
    const float xv  = (float)xc[idx];
    const float dtx = dtv * xv;
    dtsum += dtv;
#pragma unroll
    for (int s = 0; s < 16; ++s) {
      float ab = __expf(Ac[s]*dtv);
      st[s] = fmaf(ab, st[s], dtx * bs[tt][s]);
    }
  }
  const size_t qb = ((size_t)(b*INNER_ + d)*SEG_ + seg)*16;
#pragma unroll
  for (int s = 0; s < 16; ++s) Q[qb + s] = st[s];
  DTS[(size_t)(b*INNER_ + d)*SEG_ + seg] = dtsum;
}

__global__ __launch_bounds__(256)
void scan_fix(const float* __restrict__ alog, const float* __restrict__ DTS,
              float* __restrict__ QI)
{
  const int idx = blockIdx.x*256 + threadIdx.x;
  const int s = idx & 15;
  const int bd = idx >> 4;
  const int d = bd & (INNER_ - 1);
  const float A = -__expf(alog[d*16 + s]);
  float st = 0.f;
  for (int seg = 0; seg < SEG_; ++seg) {
    const size_t base = ((size_t)bd*SEG_ + seg)*16 + s;
    const float q = QI[base];
    const float dts = DTS[(size_t)bd*SEG_ + seg];
    QI[base] = st;
    st = __expf(A*dts)*st + q;
  }
}

__global__ __launch_bounds__(256)
void scan_final(const float* __restrict__ dt, const f16* __restrict__ xc,
                const float* __restrict__ bc32, const float* __restrict__ alog,
                const float* __restrict__ INIT, const f16* __restrict__ res,
                f16* __restrict__ y16)
{
  const int tid = threadIdx.x;
  const int b = blockIdx.z, seg = blockIdx.y, dc = blockIdx.x;
  const int d = dc*256 + tid;
  const int r0 = b*LSEQ_ + seg*SEGLEN_;

  __shared__ float bs[SEGLEN_][32];
  for (int i = tid; i < SEGLEN_*32; i += 256)
    bs[i >> 5][i & 31] = bc32[(size_t)(r0 + (i >> 5))*32 + (i & 31)];

  float Ac[16];
#pragma unroll
  for (int s = 0; s < 16; ++s) Ac[s] = -__expf(alog[d*16 + s]);

  float st[16];
  const size_t ib = ((size_t)(b*INNER_ + d)*SEG_ + seg)*16;
#pragma unroll
  for (int s = 0; s < 16; ++s) st[s] = INIT[ib + s];
  __syncthreads();

  for (int tt = 0; tt < SEGLEN_; ++tt) {
    const size_t idx = (size_t)(r0 + tt)*INNER_ + d;
    const float dtv = dt[idx];
    const float xv  = (float)xc[idx];
    const float dtx = dtv * xv;
    float y = 0.f;
#pragma unroll
    for (int s = 0; s < 16; ++s) {
      float ab = __expf(Ac[s]*dtv);
      st[s] = fmaf(ab, st[s], dtx * bs[tt][s]);
      y = fmaf(st[s], bs[tt][16 + s], y);
    }
    y16[idx] = (f16)(y * (float)res[idx]);
  }
}

// ---------------------------------------------------------------- launch
extern "C" void kernel_launch(void* const* d_in, const int* in_sizes, int n_in,
                              void* d_out, int out_size, void* d_ws, size_t ws_size,
                              hipStream_t stream)
{
  const float* x    = (const float*)d_in[0];
  const float* w1   = (const float*)d_in[1];
  const float* cw   = (const float*)d_in[2];
  const float* cb   = (const float*)d_in[3];
  const float* dtw  = (const float*)d_in[4];
  const float* dtb  = (const float*)d_in[5];
  const float* alog = (const float*)d_in[6];
  const float* bw   = (const float*)d_in[7];
  const float* cwt  = (const float*)d_in[8];
  const float* ow   = (const float*)d_in[9];
  float* out = (float*)d_out;

  char* ws = (char*)d_ws;
  f16*   X16   = (f16*)  (ws + 0);          // 8192x1024 f16
  f16*   W1_16 = (f16*)  (ws + 16777216);   // 4096x1024 f16
  f16*   W2_16 = (f16*)  (ws + 25165824);   // 2048x2048 f16
  f16*   BCW16 = (f16*)  (ws + 33554432);   // 32x2048 f16 (B_w;C_w)
  f16*   OW16  = (f16*)  (ws + 33685504);   // 1024x2048 f16
  f16*   RES16 = (f16*)  (ws + 37879808);   // 8192x2048 f16  silu(res)
  f16*   XC16  = (f16*)  (ws + 71434240);   // 8192x2048 f16  conv output
  f16*   XI16  = (f16*)  (ws + 104988672);  // 8192x2048 f16  x_in (pre-conv)
  f16*   Y16   = XI16;                      // aliased: XI16 dead after conv
  float* DT32  = (float*)(ws + 138543104);  // 8192x2048 f32
  float* BC32  = (float*)(ws + 205651968);  // 8192x32 f32
  float* DTS   = (float*)(ws + 206700544);  // 8192x16 f32
  float* Q     = (float*)(ws + 207224832);  // 8192x16x16 f32 (also INIT)

  cvt16<<<2048, 256, 0, stream>>>(x,   X16,   NROWS_*DIM_);
  cvt16<<<2048, 256, 0, stream>>>(w1,  W1_16, 2*INNER_*DIM_);
  cvt16<<<2048, 256, 0, stream>>>(dtw, W2_16, INNER_*INNER_);
  cvt16<<<64,   256, 0, stream>>>(bw,  BCW16, STATE_*INNER_);
  cvt16<<<64,   256, 0, stream>>>(cwt, BCW16 + (size_t)16*2048, STATE_*INNER_);
  cvt16<<<2048, 256, 0, stream>>>(ow,  OW16,  DIM_*INNER_);

  // GEMM1: xr = x @ in_proj_w^T -> x_in f16, silu(res) f16
  gemm8<0,256><<<dim3(16, 32), 512, 0, stream>>>(X16, W1_16, NROWS_, 4096, 1024,
                                                 nullptr, XI16, RES16, nullptr);
  conv_silu4<<<16384, 256, 0, stream>>>(XI16, cw, cb, XC16);
  // GEMM2: dt = softplus(xc @ dt_w^T + b)
  gemm8<1,256><<<dim3(8, 32), 512, 0, stream>>>(XC16, W2_16, NROWS_, 2048, 2048,
                                                DT32, nullptr, nullptr, dtb);
  gemm_bc<<<64, 256, 0, stream>>>(XC16, BCW16, BC32);
  scan_local<<<dim3(8, SEG_, BATCH_), 256, 0, stream>>>(DT32, XC16, BC32, alog, Q, DTS);
  scan_fix  <<<512, 256, 0, stream>>>(alog, DTS, Q);
  scan_final<<<dim3(8, SEG_, BATCH_), 256, 0, stream>>>(DT32, XC16, BC32, alog, Q, RES16, Y16);
  // GEMM3: out = (y * silu(res)) @ out_w^T
  gemm8<2,128><<<dim3(4, 64), 512, 0, stream>>>(Y16, OW16, NROWS_, 1024, 2048,
                                                out, nullptr, nullptr, nullptr);
}